// Round 4
// baseline (141.917 us; speedup 1.0000x reference)
//
#include <hip/hip_runtime.h>
#include <math.h>

#define NLAT 46
#define NLON 90
#define CH   256
#define HW   (NLAT*NLON)   // 4140
#define HWP  4160          // padded to 65*64

// attn schedule: heavy lats {0,1,44,45} sliced 45-wo per XCD; light lats banded.
#define LIGHT_PER_XCD 473
#define SLOTS_PER_XCD (45 + LIGHT_PER_XCD)

typedef __attribute__((ext_vector_type(8))) short short8;
typedef __attribute__((ext_vector_type(4))) float floatx4;

__device__ __forceinline__ ushort f2bf(float f){
  uint u = __float_as_uint(f);
  u += 0x7fff + ((u >> 16) & 1);      // RNE
  return (ushort)(u >> 16);
}
__device__ __forceinline__ float bf2f(ushort u){
  return __uint_as_float(((uint)u) << 16);
}

__device__ __forceinline__ int lower_bound_i(const int* __restrict__ a, int n, int key){
  int lo = 0, hi = n;
  while (lo < hi){ int mid = (lo + hi) >> 1; if (a[mid] < key) lo = mid + 1; else hi = mid; }
  return lo;
}

// W fp32 [k][c] -> bf16 same layout. grid(3), 256 thr.
__global__ __launch_bounds__(256) void cast_w_kernel(
    const float* __restrict__ qw, const float* __restrict__ kw, const float* __restrict__ vw,
    ushort* __restrict__ Wq, ushort* __restrict__ Wk, ushort* __restrict__ Wv)
{
  const float* W; ushort* O;
  if (blockIdx.x == 0){ W = qw; O = Wq; }
  else if (blockIdx.x == 1){ W = kw; O = Wk; }
  else { W = vw; O = Wv; }
  for (int i = threadIdx.x; i < (CH*CH)/4; i += 256){
    float4 w = ((const float4*)W)[i];
    ushort4 o;
    o.x = f2bf(w.x); o.y = f2bf(w.y); o.z = f2bf(w.z); o.w = f2bf(w.w);
    ((ushort4*)O)[i] = o;
  }
}

// X [c][hw] fp32 -> Xt [hw(pad 4160)][c] bf16. grid(65, 4, 3), 256 thr.
__global__ __launch_bounds__(256) void transpose_cast_kernel(
    const float* __restrict__ qo, const float* __restrict__ ki, const float* __restrict__ vi,
    ushort* __restrict__ qX, ushort* __restrict__ kX, ushort* __restrict__ vX)
{
  const float* X; ushort* O;
  if (blockIdx.z == 0){ X = qo; O = qX; }
  else if (blockIdx.z == 1){ X = ki; O = kX; }
  else { X = vi; O = vX; }

  __shared__ float T[64][65];   // [c][hw], pad -> 2-way (free)

  const int tid = threadIdx.x;
  const int hw0 = blockIdx.x * 64;
  const int c0  = blockIdx.y * 64;

  {
    int hwL = tid & 63;
    int cb  = tid >> 6;          // 0..3
    int hw  = hw0 + hwL;
    #pragma unroll
    for (int it = 0; it < 16; it++){
      int cL = cb + it*4;
      T[cL][hwL] = (hw < HW) ? X[(size_t)(c0+cL)*HW + hw] : 0.f;
    }
  }
  __syncthreads();
  {
    int cpair = tid & 31;        // c local = 2*cpair
    int rb    = tid >> 5;        // 0..7
    #pragma unroll
    for (int it = 0; it < 8; it++){
      int r = rb + it*8;
      float v0 = T[2*cpair][r];
      float v1 = T[2*cpair+1][r];
      ushort2 o; o.x = f2bf(v0); o.y = f2bf(v1);
      *(ushort2*)(O + (size_t)(hw0 + r)*CH + c0 + 2*cpair) = o;
    }
  }
}

// MFMA proj: D[kout][hw] = sum_c Wb[kout][c] * Xt[hw][c]  (+bias), bf16 out.
// grid(65 hw-tiles, 4 kout-tiles, 3), 256 thr. No LDS, frags from global.
__global__ __launch_bounds__(256) void proj_kernel(
    const ushort* __restrict__ qX, const ushort* __restrict__ kX, const ushort* __restrict__ vX,
    const ushort* __restrict__ Wq, const ushort* __restrict__ Wk, const ushort* __restrict__ Wv,
    const float* __restrict__ qb, const float* __restrict__ kb, const float* __restrict__ vb,
    ushort* __restrict__ qP, ushort* __restrict__ kP, ushort* __restrict__ vP)
{
  const ushort *Xt, *Wb; const float* Bias; ushort* Out;
  if (blockIdx.z == 0){ Xt = qX; Wb = Wq; Bias = qb; Out = qP; }
  else if (blockIdx.z == 1){ Xt = kX; Wb = Wk; Bias = kb; Out = kP; }
  else { Xt = vX; Wb = Wv; Bias = vb; Out = vP; }

  const int tid  = threadIdx.x;
  const int lane = tid & 63;
  const int wave = tid >> 6;
  const int hw_w   = blockIdx.x * 64 + (wave >> 1) * 32;
  const int kout_w = blockIdx.y * 64 + (wave & 1) * 32;

  const int lm = lane & 15;          // row within 16
  const int lq = lane >> 4;          // k-group 0..3

  const ushort* a0p = Wb + (size_t)(kout_w + lm)*CH + lq*8;
  const ushort* a1p = a0p + 16*CH;
  const ushort* b0p = Xt + (size_t)(hw_w + lm)*CH + lq*8;
  const ushort* b1p = b0p + 16*CH;

  floatx4 acc00 = {0,0,0,0}, acc01 = {0,0,0,0}, acc10 = {0,0,0,0}, acc11 = {0,0,0,0};

  #pragma unroll
  for (int k0 = 0; k0 < 8; k0++){
    int off = k0 * 32;
    short8 a0 = *(const short8*)(a0p + off);
    short8 a1 = *(const short8*)(a1p + off);
    short8 b0 = *(const short8*)(b0p + off);
    short8 b1 = *(const short8*)(b1p + off);
    acc00 = __builtin_amdgcn_mfma_f32_16x16x32_bf16(a0, b0, acc00, 0, 0, 0);
    acc01 = __builtin_amdgcn_mfma_f32_16x16x32_bf16(a0, b1, acc01, 0, 0, 0);
    acc10 = __builtin_amdgcn_mfma_f32_16x16x32_bf16(a1, b0, acc10, 0, 0, 0);
    acc11 = __builtin_amdgcn_mfma_f32_16x16x32_bf16(a1, b1, acc11, 0, 0, 0);
  }

  // C/D: col(lane&15)=hw-offset, row(quad*4+reg)=kout-offset
  #pragma unroll
  for (int i = 0; i < 2; i++){
    int kout = kout_w + i*16 + lq*4;
    float4 bias = *(const float4*)(Bias + kout);
    #pragma unroll
    for (int j = 0; j < 2; j++){
      floatx4 c;
      if (i == 0) c = (j == 0) ? acc00 : acc01;
      else        c = (j == 0) ? acc10 : acc11;
      int hw = hw_w + j*16 + lm;
      if (hw < HW){
        ushort4 o;
        o.x = f2bf(c[0] + bias.x);
        o.y = f2bf(c[1] + bias.y);
        o.z = f2bf(c[2] + bias.z);
        o.w = f2bf(c[3] + bias.w);
        *(ushort4*)(Out + (size_t)hw*CH + kout) = o;
      }
    }
  }
}

__device__ __forceinline__ float4 ld_bf4(const ushort* p, int lane){
  ushort4 u = ((const ushort4*)p)[lane];
  float4 f;
  f.x = bf2f(u.x); f.y = bf2f(u.y); f.z = bf2f(u.z); f.w = bf2f(u.w);
  return f;
}

// Block per (t,wo), XCD-balanced schedule, bf16 q/k/v, no max-subtraction.
__global__ __launch_bounds__(256) void attn_kernel(
    const ushort* __restrict__ qP, const ushort* __restrict__ kP, const ushort* __restrict__ vP,
    const float* __restrict__ quad_w, const int* __restrict__ row_ids,
    const int* __restrict__ col_idx, int nnz, float* __restrict__ out)
{
  const int bid  = blockIdx.x;
  const int xcd  = bid & 7;
  const int slot = bid >> 3;

  int t, wo;
  if (slot < 45){
    int hu   = xcd * 45 + slot;
    int hidx = hu / 90;
    t  = (hidx < 2) ? hidx : 42 + hidx;
    wo = hu - hidx * 90;
  } else {
    int lu = xcd * LIGHT_PER_XCD + (slot - 45);
    if (lu >= 42 * NLON) return;
    int li = lu / NLON;
    t  = li + 2;
    wo = lu - li * NLON;
  }

  const int tid  = threadIdx.x;
  const int lane = tid & 63;
  const int wave = tid >> 6;

  const int start = lower_bound_i(row_ids, nnz, t);
  const int end   = lower_bound_i(row_ids, nnz, t + 1);

  const float4 qf = ld_bf4(qP + (size_t)(t * NLON + wo) * CH, lane);

  float denom = 0.f;
  float4 acc = make_float4(0.f, 0.f, 0.f, 0.f);

  int n = start + wave;
  for (; n + 4 < end; n += 8){
    int ciA = col_idx[n];
    int hiA = ciA / NLON;
    int wiA = ciA - hiA*NLON + wo; if (wiA >= NLON) wiA -= NLON;
    size_t offA = ((size_t)hiA*NLON + wiA) * CH;
    int ciB = col_idx[n + 4];
    int hiB = ciB / NLON;
    int wiB = ciB - hiB*NLON + wo; if (wiB >= NLON) wiB -= NLON;
    size_t offB = ((size_t)hiB*NLON + wiB) * CH;

    float4 kfA = ld_bf4(kP + offA, lane);
    float4 kfB = ld_bf4(kP + offB, lane);
    float sA = qf.x*kfA.x + qf.y*kfA.y + qf.z*kfA.z + qf.w*kfA.w;
    float sB = qf.x*kfB.x + qf.y*kfB.y + qf.z*kfB.z + qf.w*kfB.w;
    #pragma unroll
    for (int o = 32; o >= 1; o >>= 1){
      sA += __shfl_xor(sA, o, 64);
      sB += __shfl_xor(sB, o, 64);
    }
    float eA = __expf(sA) * quad_w[hiA];
    float eB = __expf(sB) * quad_w[hiB];
    float4 vfA = ld_bf4(vP + offA, lane);
    float4 vfB = ld_bf4(vP + offB, lane);
    denom += eA + eB;
    acc.x += eA*vfA.x + eB*vfB.x;
    acc.y += eA*vfA.y + eB*vfB.y;
    acc.z += eA*vfA.z + eB*vfB.z;
    acc.w += eA*vfA.w + eB*vfB.w;
  }
  if (n < end){
    int ci = col_idx[n];
    int hi = ci / NLON;
    int wi = ci - hi*NLON + wo; if (wi >= NLON) wi -= NLON;
    size_t off = ((size_t)hi*NLON + wi) * CH;
    float4 kf = ld_bf4(kP + off, lane);
    float s = qf.x*kf.x + qf.y*kf.y + qf.z*kf.z + qf.w*kf.w;
    #pragma unroll
    for (int o = 32; o >= 1; o >>= 1) s += __shfl_xor(s, o, 64);
    float e = __expf(s) * quad_w[hi];
    float4 vf = ld_bf4(vP + off, lane);
    denom += e;
    acc.x += e*vf.x; acc.y += e*vf.y; acc.z += e*vf.z; acc.w += e*vf.w;
  }

  __shared__ float sden[4];
  __shared__ float sacc[4][CH];
  if (lane == 0) sden[wave] = denom;
  sacc[wave][lane*4+0] = acc.x;
  sacc[wave][lane*4+1] = acc.y;
  sacc[wave][lane*4+2] = acc.z;
  sacc[wave][lane*4+3] = acc.w;
  __syncthreads();

  const float den = sden[0] + sden[1] + sden[2] + sden[3];
  const float num = sacc[0][tid] + sacc[1][tid] + sacc[2][tid] + sacc[3][tid];
  out[(size_t)tid * HW + t * NLON + wo] = num / den;
}

extern "C" void kernel_launch(void* const* d_in, const int* in_sizes, int n_in,
                              void* d_out, int out_size, void* d_ws, size_t ws_size,
                              hipStream_t stream)
{
  const float* qo   = (const float*)d_in[0];
  const float* ki   = (const float*)d_in[1];
  const float* vi   = (const float*)d_in[2];
  const float* qw   = (const float*)d_in[3];
  const float* kw   = (const float*)d_in[4];
  const float* vw   = (const float*)d_in[5];
  const float* qb   = (const float*)d_in[6];
  const float* kb   = (const float*)d_in[7];
  const float* vb   = (const float*)d_in[8];
  const float* quad = (const float*)d_in[9];
  const int* row_ids = (const int*)d_in[10];
  const int* col_idx = (const int*)d_in[11];
  const int nnz = in_sizes[10];

  ushort* ws = (ushort*)d_ws;
  const size_t TSZ = (size_t)HWP * CH;          // 1,064,960
  ushort* qX = ws;              ushort* kX = qX + TSZ;  ushort* vX = kX + TSZ;
  ushort* qP = vX + TSZ;        ushort* kP = qP + TSZ;  ushort* vP = kP + TSZ;
  ushort* Wq = vP + TSZ;        ushort* Wk = Wq + CH*CH; ushort* Wv = Wk + CH*CH;

  cast_w_kernel<<<dim3(3), 256, 0, stream>>>(qw, kw, vw, Wq, Wk, Wv);
  transpose_cast_kernel<<<dim3(65, 4, 3), 256, 0, stream>>>(qo, ki, vi, qX, kX, vX);
  proj_kernel<<<dim3(65, 4, 3), 256, 0, stream>>>(qX, kX, vX, Wq, Wk, Wv, qb, kb, vb, qP, kP, vP);
  attn_kernel<<<dim3(8 * SLOTS_PER_XCD), 256, 0, stream>>>(qP, kP, vP, quad, row_ids, col_idx, nnz, (float*)d_out);
}

// Round 5
// 124.149 us; speedup vs baseline: 1.1431x; 1.1431x over previous
//
#include <hip/hip_runtime.h>
#include <math.h>

#define NLAT 46
#define NLON 90
#define CH   256
#define HW   (NLAT*NLON)   // 4140
#define HWP  4160          // 130*32
#define HWT  32            // hw rows per proj block
#define NHT  130           // hw tiles
#define XSTR 264           // LDS row stride (ushorts): 528B = 16B-aligned, 2-way-free b128 reads

// attn schedule: heavy lats {0,1,44,45} sliced 45-wo per XCD; light lats banded.
#define LIGHT_PER_XCD 473
#define SLOTS_PER_XCD (45 + LIGHT_PER_XCD)

typedef __attribute__((ext_vector_type(8))) short short8;
typedef __attribute__((ext_vector_type(4))) float floatx4;

__device__ __forceinline__ ushort f2bf(float f){
  uint u = __float_as_uint(f);
  u += 0x7fff + ((u >> 16) & 1);      // RNE
  return (ushort)(u >> 16);
}
__device__ __forceinline__ float bf2f(ushort u){
  return __uint_as_float(((uint)u) << 16);
}

__device__ __forceinline__ int lower_bound_i(const int* __restrict__ a, int n, int key){
  int lo = 0, hi = n;
  while (lo < hi){ int mid = (lo + hi) >> 1; if (a[mid] < key) lo = mid + 1; else hi = mid; }
  return lo;
}

// W fp32 [k][c] -> bf16 same layout. grid(8,3), 256 thr.
__global__ __launch_bounds__(256) void cast_w_kernel(
    const float* __restrict__ qw, const float* __restrict__ kw, const float* __restrict__ vw,
    ushort* __restrict__ Wq, ushort* __restrict__ Wk, ushort* __restrict__ Wv)
{
  const float* W; ushort* O;
  if (blockIdx.y == 0){ W = qw; O = Wq; }
  else if (blockIdx.y == 1){ W = kw; O = Wk; }
  else { W = vw; O = Wv; }
  for (int i = blockIdx.x * 256 + threadIdx.x; i < (CH*CH)/4; i += 8*256){
    float4 w = ((const float4*)W)[i];
    ushort4 o;
    o.x = f2bf(w.x); o.y = f2bf(w.y); o.z = f2bf(w.z); o.w = f2bf(w.w);
    ((ushort4*)O)[i] = o;
  }
}

// Fused transpose+cast+GEMM: Out[hw][kout] = sum_c W[kout][c]*X[c][hw] + bias.
// Block = 32 hw x 256 kout; 4 waves each own 64 kout. X tile transposed
// through LDS (bf16), A-frags from L2-resident bf16 W, no intermediate Xt.
__global__ __launch_bounds__(256) void fproj_kernel(
    const float* __restrict__ qo, const float* __restrict__ ki, const float* __restrict__ vi,
    const ushort* __restrict__ Wq, const ushort* __restrict__ Wk, const ushort* __restrict__ Wv,
    const float* __restrict__ qb, const float* __restrict__ kb, const float* __restrict__ vb,
    ushort* __restrict__ qP, ushort* __restrict__ kP, ushort* __restrict__ vP)
{
  const float* X; const ushort* Wb; const float* Bias; ushort* Out;
  if (blockIdx.y == 0){ X = qo; Wb = Wq; Bias = qb; Out = qP; }
  else if (blockIdx.y == 1){ X = ki; Wb = Wk; Bias = kb; Out = kP; }
  else { X = vi; Wb = Wv; Bias = vb; Out = vP; }

  __shared__ ushort Xs[HWT][XSTR];

  const int tid = threadIdx.x;
  const int hw0 = blockIdx.x * HWT;

  // ---- stage: X[c][hw] fp32 -> Xs[hwL][c] bf16 ----
  {
    int hwL = tid & 31;
    int cb  = tid >> 5;              // 0..7, owns c in [cb*32, cb*32+32)
    int hw  = hw0 + hwL;
    bool ok = hw < HW;
    const float* Xp = X + (size_t)(cb*32)*HW + (ok ? hw : 0);
    #pragma unroll
    for (int g = 0; g < 4; g++){
      short8 pk;
      #pragma unroll
      for (int u = 0; u < 8; u++){
        float f = ok ? Xp[(size_t)(g*8 + u)*HW] : 0.f;
        pk[u] = (short)f2bf(f);
      }
      *(short8*)(&Xs[hwL][cb*32 + g*8]) = pk;
    }
  }
  __syncthreads();

  const int lane = tid & 63;
  const int wave = tid >> 6;
  const int lm = lane & 15;
  const int lq = lane >> 4;
  const int kout_w = wave * 64;

  const ushort* Ap = Wb + (size_t)(kout_w + lm)*CH + lq*8;

  floatx4 acc[4][2];
  #pragma unroll
  for (int i = 0; i < 4; i++)
    #pragma unroll
    for (int j = 0; j < 2; j++) acc[i][j] = (floatx4){0,0,0,0};

  #pragma unroll
  for (int k0 = 0; k0 < 8; k0++){
    short8 a[4], b[2];
    #pragma unroll
    for (int i = 0; i < 4; i++)
      a[i] = *(const short8*)(Ap + (size_t)i*16*CH + k0*32);
    #pragma unroll
    for (int j = 0; j < 2; j++)
      b[j] = *(const short8*)(&Xs[j*16 + lm][lq*8 + k0*32]);
    #pragma unroll
    for (int i = 0; i < 4; i++)
      #pragma unroll
      for (int j = 0; j < 2; j++)
        acc[i][j] = __builtin_amdgcn_mfma_f32_16x16x32_bf16(a[i], b[j], acc[i][j], 0, 0, 0);
  }

  // C/D: col(lane&15)=hw, row(lq*4+r)=kout
  #pragma unroll
  for (int i = 0; i < 4; i++){
    int kout = kout_w + i*16 + lq*4;
    float4 bias = *(const float4*)(Bias + kout);
    #pragma unroll
    for (int j = 0; j < 2; j++){
      int hw = hw0 + j*16 + lm;
      if (hw < HW){
        ushort4 o;
        o.x = f2bf(acc[i][j][0] + bias.x);
        o.y = f2bf(acc[i][j][1] + bias.y);
        o.z = f2bf(acc[i][j][2] + bias.z);
        o.w = f2bf(acc[i][j][3] + bias.w);
        *(ushort4*)(Out + (size_t)hw*CH + kout) = o;
      }
    }
  }
}

__device__ __forceinline__ float4 ld_bf4(const ushort* p, int lane){
  ushort4 u = ((const ushort4*)p)[lane];
  float4 f;
  f.x = bf2f(u.x); f.y = bf2f(u.y); f.z = bf2f(u.z); f.w = bf2f(u.w);
  return f;
}

// Block per (t,wo), XCD-balanced schedule, bf16 q/k/v, no max-subtraction.
__global__ __launch_bounds__(256) void attn_kernel(
    const ushort* __restrict__ qP, const ushort* __restrict__ kP, const ushort* __restrict__ vP,
    const float* __restrict__ quad_w, const int* __restrict__ row_ids,
    const int* __restrict__ col_idx, int nnz, float* __restrict__ out)
{
  const int bid  = blockIdx.x;
  const int xcd  = bid & 7;
  const int slot = bid >> 3;

  int t, wo;
  if (slot < 45){
    int hu   = xcd * 45 + slot;
    int hidx = hu / 90;
    t  = (hidx < 2) ? hidx : 42 + hidx;
    wo = hu - hidx * 90;
  } else {
    int lu = xcd * LIGHT_PER_XCD + (slot - 45);
    if (lu >= 42 * NLON) return;
    int li = lu / NLON;
    t  = li + 2;
    wo = lu - li * NLON;
  }

  const int tid  = threadIdx.x;
  const int lane = tid & 63;
  const int wave = tid >> 6;

  const int start = lower_bound_i(row_ids, nnz, t);
  const int end   = lower_bound_i(row_ids, nnz, t + 1);

  const float4 qf = ld_bf4(qP + (size_t)(t * NLON + wo) * CH, lane);

  float denom = 0.f;
  float4 acc = make_float4(0.f, 0.f, 0.f, 0.f);

  int n = start + wave;
  for (; n + 4 < end; n += 8){
    int ciA = col_idx[n];
    int hiA = ciA / NLON;
    int wiA = ciA - hiA*NLON + wo; if (wiA >= NLON) wiA -= NLON;
    size_t offA = ((size_t)hiA*NLON + wiA) * CH;
    int ciB = col_idx[n + 4];
    int hiB = ciB / NLON;
    int wiB = ciB - hiB*NLON + wo; if (wiB >= NLON) wiB -= NLON;
    size_t offB = ((size_t)hiB*NLON + wiB) * CH;

    float4 kfA = ld_bf4(kP + offA, lane);
    float4 kfB = ld_bf4(kP + offB, lane);
    float sA = qf.x*kfA.x + qf.y*kfA.y + qf.z*kfA.z + qf.w*kfA.w;
    float sB = qf.x*kfB.x + qf.y*kfB.y + qf.z*kfB.z + qf.w*kfB.w;
    #pragma unroll
    for (int o = 32; o >= 1; o >>= 1){
      sA += __shfl_xor(sA, o, 64);
      sB += __shfl_xor(sB, o, 64);
    }
    float eA = __expf(sA) * quad_w[hiA];
    float eB = __expf(sB) * quad_w[hiB];
    float4 vfA = ld_bf4(vP + offA, lane);
    float4 vfB = ld_bf4(vP + offB, lane);
    denom += eA + eB;
    acc.x += eA*vfA.x + eB*vfB.x;
    acc.y += eA*vfA.y + eB*vfB.y;
    acc.z += eA*vfA.z + eB*vfB.z;
    acc.w += eA*vfA.w + eB*vfB.w;
  }
  if (n < end){
    int ci = col_idx[n];
    int hi = ci / NLON;
    int wi = ci - hi*NLON + wo; if (wi >= NLON) wi -= NLON;
    size_t off = ((size_t)hi*NLON + wi) * CH;
    float4 kf = ld_bf4(kP + off, lane);
    float s = qf.x*kf.x + qf.y*kf.y + qf.z*kf.z + qf.w*kf.w;
    #pragma unroll
    for (int o = 32; o >= 1; o >>= 1) s += __shfl_xor(s, o, 64);
    float e = __expf(s) * quad_w[hi];
    float4 vf = ld_bf4(vP + off, lane);
    denom += e;
    acc.x += e*vf.x; acc.y += e*vf.y; acc.z += e*vf.z; acc.w += e*vf.w;
  }

  __shared__ float sden[4];
  __shared__ float sacc[4][CH];
  if (lane == 0) sden[wave] = denom;
  sacc[wave][lane*4+0] = acc.x;
  sacc[wave][lane*4+1] = acc.y;
  sacc[wave][lane*4+2] = acc.z;
  sacc[wave][lane*4+3] = acc.w;
  __syncthreads();

  const float den = sden[0] + sden[1] + sden[2] + sden[3];
  const float num = sacc[0][tid] + sacc[1][tid] + sacc[2][tid] + sacc[3][tid];
  out[(size_t)tid * HW + t * NLON + wo] = num / den;
}

extern "C" void kernel_launch(void* const* d_in, const int* in_sizes, int n_in,
                              void* d_out, int out_size, void* d_ws, size_t ws_size,
                              hipStream_t stream)
{
  const float* qo   = (const float*)d_in[0];
  const float* ki   = (const float*)d_in[1];
  const float* vi   = (const float*)d_in[2];
  const float* qw   = (const float*)d_in[3];
  const float* kw   = (const float*)d_in[4];
  const float* vw   = (const float*)d_in[5];
  const float* qb   = (const float*)d_in[6];
  const float* kb   = (const float*)d_in[7];
  const float* vb   = (const float*)d_in[8];
  const float* quad = (const float*)d_in[9];
  const int* row_ids = (const int*)d_in[10];
  const int* col_idx = (const int*)d_in[11];
  const int nnz = in_sizes[10];

  ushort* ws = (ushort*)d_ws;
  const size_t TSZ = (size_t)HWP * CH;
  ushort* qP = ws;        ushort* kP = qP + TSZ;   ushort* vP = kP + TSZ;
  ushort* Wq = vP + TSZ;  ushort* Wk = Wq + CH*CH; ushort* Wv = Wk + CH*CH;

  cast_w_kernel<<<dim3(8, 3), 256, 0, stream>>>(qw, kw, vw, Wq, Wk, Wv);
  fproj_kernel<<<dim3(NHT, 3), 256, 0, stream>>>(qo, ki, vi, Wq, Wk, Wv, qb, kb, vb, qP, kP, vP);
  attn_kernel<<<dim3(8 * SLOTS_PER_XCD), 256, 0, stream>>>(qP, kP, vP, quad, row_ids, col_idx, nnz, (float*)d_out);
}

// Round 6
// 121.073 us; speedup vs baseline: 1.1722x; 1.0254x over previous
//
#include <hip/hip_runtime.h>
#include <math.h>

#define NLAT 46
#define NLON 90
#define CH   256
#define HW   (NLAT*NLON)   // 4140
#define HWP  4160
#define HWT  32            // hw rows per proj block
#define NHT  130           // hw tiles
#define XSTR 264           // LDS row stride (ushorts)

// attn schedule: heavy lats {0,1,44,45} sliced 45-wo per XCD; light lats banded.
#define LIGHT_PER_XCD 473
#define SLOTS_PER_XCD (45 + LIGHT_PER_XCD)

typedef __attribute__((ext_vector_type(8))) short short8;
typedef __attribute__((ext_vector_type(4))) float floatx4;

__device__ __forceinline__ ushort f2bf(float f){
  uint u = __float_as_uint(f);
  u += 0x7fff + ((u >> 16) & 1);      // RNE
  return (ushort)(u >> 16);
}
__device__ __forceinline__ float bf2f(ushort u){
  return __uint_as_float(((uint)u) << 16);
}
__device__ __forceinline__ float bf2fs(short s){
  return __uint_as_float(((uint)(ushort)s) << 16);
}

__device__ __forceinline__ int lower_bound_i(const int* __restrict__ a, int n, int key){
  int lo = 0, hi = n;
  while (lo < hi){ int mid = (lo + hi) >> 1; if (a[mid] < key) lo = mid + 1; else hi = mid; }
  return lo;
}

// Fused cast+transpose+GEMM: Out[hw][kout] = sum_c W[kout][c]*X[c][hw] + bias.
// Block = 32 hw x 256 kout; 4 waves each own 64 kout. X transposed through
// LDS (bf16); W fp32 frags loaded from L2 and cast inline.
__global__ __launch_bounds__(256) void fproj_kernel(
    const float* __restrict__ qo, const float* __restrict__ ki, const float* __restrict__ vi,
    const float* __restrict__ qw, const float* __restrict__ kw, const float* __restrict__ vw,
    const float* __restrict__ qb, const float* __restrict__ kb, const float* __restrict__ vb,
    ushort* __restrict__ qP, ushort* __restrict__ kP, ushort* __restrict__ vP)
{
  const float* X; const float* Wf; const float* Bias; ushort* Out;
  if (blockIdx.y == 0){ X = qo; Wf = qw; Bias = qb; Out = qP; }
  else if (blockIdx.y == 1){ X = ki; Wf = kw; Bias = kb; Out = kP; }
  else { X = vi; Wf = vw; Bias = vb; Out = vP; }

  __shared__ ushort Xs[HWT][XSTR];

  const int tid = threadIdx.x;
  const int hw0 = blockIdx.x * HWT;

  // ---- stage: X[c][hw] fp32 -> Xs[hwL][c] bf16 ----
  {
    int hwL = tid & 31;
    int cb  = tid >> 5;              // 0..7, owns c in [cb*32, cb*32+32)
    int hw  = hw0 + hwL;
    bool ok = hw < HW;
    const float* Xp = X + (size_t)(cb*32)*HW + (ok ? hw : 0);
    #pragma unroll
    for (int g = 0; g < 4; g++){
      short8 pk;
      #pragma unroll
      for (int u = 0; u < 8; u++){
        float f = ok ? Xp[(size_t)(g*8 + u)*HW] : 0.f;
        pk[u] = (short)f2bf(f);
      }
      *(short8*)(&Xs[hwL][cb*32 + g*8]) = pk;
    }
  }
  __syncthreads();

  const int lane = tid & 63;
  const int wave = tid >> 6;
  const int lm = lane & 15;
  const int lq = lane >> 4;
  const int kout_w = wave * 64;

  const float* Apf = Wf + (size_t)(kout_w + lm)*CH + lq*8;

  floatx4 acc[4][2];
  #pragma unroll
  for (int i = 0; i < 4; i++)
    #pragma unroll
    for (int j = 0; j < 2; j++) acc[i][j] = (floatx4){0,0,0,0};

  #pragma unroll
  for (int k0 = 0; k0 < 8; k0++){
    short8 a[4], b[2];
    #pragma unroll
    for (int i = 0; i < 4; i++){
      const float* p = Apf + (size_t)i*16*CH + k0*32;
      float4 w0 = *(const float4*)p;
      float4 w1 = *(const float4*)(p + 4);
      a[i][0] = (short)f2bf(w0.x); a[i][1] = (short)f2bf(w0.y);
      a[i][2] = (short)f2bf(w0.z); a[i][3] = (short)f2bf(w0.w);
      a[i][4] = (short)f2bf(w1.x); a[i][5] = (short)f2bf(w1.y);
      a[i][6] = (short)f2bf(w1.z); a[i][7] = (short)f2bf(w1.w);
    }
    #pragma unroll
    for (int j = 0; j < 2; j++)
      b[j] = *(const short8*)(&Xs[j*16 + lm][lq*8 + k0*32]);
    #pragma unroll
    for (int i = 0; i < 4; i++)
      #pragma unroll
      for (int j = 0; j < 2; j++)
        acc[i][j] = __builtin_amdgcn_mfma_f32_16x16x32_bf16(a[i], b[j], acc[i][j], 0, 0, 0);
  }

  // C/D: col(lane&15)=hw, row(lq*4+r)=kout
  #pragma unroll
  for (int i = 0; i < 4; i++){
    int kout = kout_w + i*16 + lq*4;
    float4 bias = *(const float4*)(Bias + kout);
    #pragma unroll
    for (int j = 0; j < 2; j++){
      int hw = hw0 + j*16 + lm;
      if (hw < HW){
        ushort4 o;
        o.x = f2bf(acc[i][j][0] + bias.x);
        o.y = f2bf(acc[i][j][1] + bias.y);
        o.z = f2bf(acc[i][j][2] + bias.z);
        o.w = f2bf(acc[i][j][3] + bias.w);
        *(ushort4*)(Out + (size_t)hw*CH + kout) = o;
      }
    }
  }
}

// Block per (t,wo). Lane = (visit-slot g=lane>>4, channel-group gl=lane&15):
// 4 visits in flight per wave, 16 channels per lane, 4 shuffle levels per dot.
__global__ __launch_bounds__(256) void attn_kernel(
    const ushort* __restrict__ qP, const ushort* __restrict__ kP, const ushort* __restrict__ vP,
    const float* __restrict__ quad_w, const int* __restrict__ row_ids,
    const int* __restrict__ col_idx, int nnz, float* __restrict__ out)
{
  const int bid  = blockIdx.x;
  const int xcd  = bid & 7;
  const int slot = bid >> 3;

  int t, wo;
  if (slot < 45){
    int hu   = xcd * 45 + slot;
    int hidx = hu / 90;
    t  = (hidx < 2) ? hidx : 42 + hidx;
    wo = hu - hidx * 90;
  } else {
    int lu = xcd * LIGHT_PER_XCD + (slot - 45);
    if (lu >= 42 * NLON) return;
    int li = lu / NLON;
    t  = li + 2;
    wo = lu - li * NLON;
  }

  const int tid  = threadIdx.x;
  const int lane = tid & 63;
  const int wave = tid >> 6;
  const int g    = lane >> 4;
  const int gl   = lane & 15;

  const int start = lower_bound_i(row_ids, nnz, t);
  const int end   = lower_bound_i(row_ids, nnz, t + 1);

  // q channels [gl*16, gl*16+16)
  float qf[16];
  {
    const ushort* qrow = qP + (size_t)(t * NLON + wo) * CH + gl*16;
    short8 q0 = *(const short8*)(qrow);
    short8 q1 = *(const short8*)(qrow + 8);
    #pragma unroll
    for (int u = 0; u < 8; u++){ qf[u] = bf2fs(q0[u]); qf[8+u] = bf2fs(q1[u]); }
  }

  float den = 0.f;
  float acc[16];
  #pragma unroll
  for (int u = 0; u < 16; u++) acc[u] = 0.f;

  for (int n0 = start + wave*4 + g; n0 < end; n0 += 16){
    int ci = col_idx[n0];
    int hi = ci / NLON;
    int wi = ci - hi*NLON + wo; if (wi >= NLON) wi -= NLON;
    size_t off = ((size_t)hi*NLON + wi) * CH + gl*16;

    const short8* kp8 = (const short8*)(kP + off);
    short8 k0 = kp8[0], k1 = kp8[1];
    float s = 0.f;
    #pragma unroll
    for (int u = 0; u < 8; u++){
      s += qf[u]   * bf2fs(k0[u]);
      s += qf[8+u] * bf2fs(k1[u]);
    }
    s += __shfl_xor(s, 1, 64);
    s += __shfl_xor(s, 2, 64);
    s += __shfl_xor(s, 4, 64);
    s += __shfl_xor(s, 8, 64);

    float e = __expf(s) * quad_w[hi];
    const short8* vp8 = (const short8*)(vP + off);
    short8 v0 = vp8[0], v1 = vp8[1];
    den += e;
    #pragma unroll
    for (int u = 0; u < 8; u++){
      acc[u]   += e * bf2fs(v0[u]);
      acc[8+u] += e * bf2fs(v1[u]);
    }
  }

  // merge the 4 visit-slots within the wave
  #pragma unroll
  for (int u = 0; u < 16; u++){
    acc[u] += __shfl_xor(acc[u], 16, 64);
    acc[u] += __shfl_xor(acc[u], 32, 64);
  }
  den += __shfl_xor(den, 16, 64);
  den += __shfl_xor(den, 32, 64);

  __shared__ float sden[4];
  __shared__ float sacc[4][CH];
  if (lane == 0) sden[wave] = den;
  if (g == 0){
    #pragma unroll
    for (int u = 0; u < 16; u++) sacc[wave][gl*16 + u] = acc[u];
  }
  __syncthreads();

  const float D   = sden[0] + sden[1] + sden[2] + sden[3];
  const float num = sacc[0][tid] + sacc[1][tid] + sacc[2][tid] + sacc[3][tid];
  out[(size_t)tid * HW + t * NLON + wo] = num / D;
}

extern "C" void kernel_launch(void* const* d_in, const int* in_sizes, int n_in,
                              void* d_out, int out_size, void* d_ws, size_t ws_size,
                              hipStream_t stream)
{
  const float* qo   = (const float*)d_in[0];
  const float* ki   = (const float*)d_in[1];
  const float* vi   = (const float*)d_in[2];
  const float* qw   = (const float*)d_in[3];
  const float* kw   = (const float*)d_in[4];
  const float* vw   = (const float*)d_in[5];
  const float* qb   = (const float*)d_in[6];
  const float* kb   = (const float*)d_in[7];
  const float* vb   = (const float*)d_in[8];
  const float* quad = (const float*)d_in[9];
  const int* row_ids = (const int*)d_in[10];
  const int* col_idx = (const int*)d_in[11];
  const int nnz = in_sizes[10];

  ushort* ws = (ushort*)d_ws;
  const size_t TSZ = (size_t)HWP * CH;
  ushort* qP = ws;  ushort* kP = qP + TSZ;  ushort* vP = kP + TSZ;

  fproj_kernel<<<dim3(NHT, 3), 256, 0, stream>>>(qo, ki, vi, qw, kw, vw, qb, kb, vb, qP, kP, vP);
  attn_kernel<<<dim3(8 * SLOTS_PER_XCD), 256, 0, stream>>>(qP, kP, vP, quad, row_ids, col_idx, nnz, (float*)d_out);
}